// Round 3
// baseline (766.964 us; speedup 1.0000x reference)
//
#include <hip/hip_runtime.h>
#include <math.h>

#define B_ 32
#define T_ 2048
#define H_ 1024

typedef __bf16 bf16x8 __attribute__((ext_vector_type(8)));
typedef float f32x4 __attribute__((ext_vector_type(4)));

__device__ __forceinline__ unsigned short f2bf(float f) {
  unsigned int u = __float_as_uint(f);
  u += 0x7fffu + ((u >> 16) & 1u);   // round-to-nearest-even (finite inputs)
  return (unsigned short)(u >> 16);
}

__device__ __forceinline__ float bf2f(unsigned short s) {
  return __uint_as_float(((unsigned int)s) << 16);
}

__device__ __forceinline__ float fast_tanh(float x) {
  float e = __expf(2.0f * x);
  return 1.0f - __fdividef(2.0f, e + 1.0f);  // saturates correctly at +-1
}

// blk < 128:    hxb[b,o] = x[b,:].Wq[o,:] + bq[o] + bm[o]
// blk < 1152:   Wm fp32 -> bf16
// blk < 1248:   zero logits (64 blocks) + out_c (32 blocks)
// blk >= 1248:  ctx fp32 -> bf16 (only when ws has room)
__global__ void prep_kernel(const float* __restrict__ x, const float* __restrict__ Wq,
                            const float* __restrict__ bq, const float* __restrict__ bm,
                            const float* __restrict__ Wm, const float* __restrict__ ctx,
                            float* __restrict__ hxb, unsigned short* __restrict__ wmb,
                            unsigned short* __restrict__ ctxb,
                            float* __restrict__ logits, float* __restrict__ outc) {
  int blk = blockIdx.x, tid = threadIdx.x;
  if (blk < 128) {
    int idx = (blk << 8) + tid;
    int b = idx >> 10, o = idx & (H_ - 1);
    const float4* xr = (const float4*)(x + b * H_);
    const float4* wr = (const float4*)(Wq + o * H_);
    float s = 0.f;
#pragma unroll 8
    for (int h = 0; h < H_ / 4; ++h) {
      float4 xv = xr[h], wv = wr[h];
      s += xv.x * wv.x + xv.y * wv.y + xv.z * wv.z + xv.w * wv.w;
    }
    hxb[idx] = s + bq[o] + bm[o];
  } else if (blk < 1152) {
    int i = ((blk - 128) << 10) + (tid << 2);
    float4 wv = *(const float4*)(Wm + i);
    *(ushort4*)(wmb + i) = make_ushort4(f2bf(wv.x), f2bf(wv.y), f2bf(wv.z), f2bf(wv.w));
  } else if (blk < 1248) {
    int zblk = blk - 1152;
    if (zblk < 64) {
      *(float4*)(logits + (zblk << 10) + (tid << 2)) = (float4){0.f, 0.f, 0.f, 0.f};
    } else {
      *(float4*)(outc + ((zblk - 64) << 10) + (tid << 2)) = (float4){0.f, 0.f, 0.f, 0.f};
    }
  } else {
    size_t i = ((size_t)(blk - 1248) << 11) + ((size_t)tid << 3);
    float4 a = *(const float4*)(ctx + i);
    float4 c = *(const float4*)(ctx + i + 4);
    *(ushort4*)(ctxb + i) = make_ushort4(f2bf(a.x), f2bf(a.y), f2bf(a.z), f2bf(a.w));
    *(ushort4*)(ctxb + i + 4) = make_ushort4(f2bf(c.x), f2bf(c.y), f2bf(c.z), f2bf(c.w));
  }
}

// Grid 4096: blockIdx.x = ot*512 + (b*16 + tt). One 128t x 128o tile per block.
// A (ctx bf16) staged in padded LDS; B (Wm bf16, L2-resident) loaded straight into
// fragments from global. Partial logits (sum over this block's 128 o) atomicAdd'ed
// into global logits (zeroed by prep).
template <bool PRECONV>
__global__ __launch_bounds__(256) void score_kernel(
    const float* __restrict__ ctxf, const unsigned short* __restrict__ ctxb,
    const unsigned short* __restrict__ wmb,
    const float* __restrict__ hxb, const float* __restrict__ v,
    float* logits) {
  __shared__ __align__(16) unsigned short As[128][72];
  __shared__ float part[128];

  int tid = threadIdx.x;
  int xx = blockIdx.x;
  int ot = xx >> 9;
  int bt = xx & 511;
  int b = bt >> 4;
  int t0 = (bt & 15) << 7;
  int o0 = ot << 7;
  if (tid < 128) part[tid] = 0.f;

  int lane = tid & 63;
  int wave = tid >> 6;
  int wm = (wave >> 1) << 6;  // wave t-offset (0/64)
  int wn = (wave & 1) << 6;   // wave o-offset (0/64)
  int q = lane >> 4;
  int m = lane & 15;
  const unsigned short* cb = PRECONV ? (ctxb + ((size_t)b * T_ + t0) * H_) : nullptr;
  const float* cf = PRECONV ? nullptr : (ctxf + ((size_t)b * T_ + t0) * H_);

  int ar = tid >> 3;        // staging row 0..31 (+32 per rep)
  int ac = (tid & 7) << 3;  // staging col granule (ushort units)

  f32x4 acc[4][4];
#pragma unroll
  for (int i = 0; i < 4; ++i)
#pragma unroll
    for (int j = 0; j < 4; ++j) acc[i][j] = (f32x4){0.f, 0.f, 0.f, 0.f};

  for (int k0 = 0; k0 < H_; k0 += 64) {
    __syncthreads();
#pragma unroll
    for (int rep = 0; rep < 4; ++rep) {
      int row = ar + (rep << 5);
      if (PRECONV) {
        *(uint4*)(&As[row][ac]) = *(const uint4*)(cb + (size_t)row * H_ + k0 + ac);
      } else {
        const float* src = cf + (size_t)row * H_ + k0 + ac;
        float4 f0 = *(const float4*)(src);
        float4 f1 = *(const float4*)(src + 4);
        *(ushort4*)(&As[row][ac]) =
            make_ushort4(f2bf(f0.x), f2bf(f0.y), f2bf(f0.z), f2bf(f0.w));
        *(ushort4*)(&As[row][ac + 4]) =
            make_ushort4(f2bf(f1.x), f2bf(f1.y), f2bf(f1.z), f2bf(f1.w));
      }
    }
    __syncthreads();
#pragma unroll
    for (int kk = 0; kk < 2; ++kk) {
      bf16x8 af[4], bfr[4];
      const unsigned short* wp =
          wmb + (size_t)(o0 + wn + m) * H_ + k0 + (kk << 5) + (q << 3);
#pragma unroll
      for (int j = 0; j < 4; ++j)
        bfr[j] = *(const bf16x8*)(wp + ((size_t)(j << 4) * H_));
#pragma unroll
      for (int i = 0; i < 4; ++i)
        af[i] = *(const bf16x8*)(&As[wm + (i << 4) + m][(kk << 5) + (q << 3)]);
#pragma unroll
      for (int i = 0; i < 4; ++i)
#pragma unroll
        for (int j = 0; j < 4; ++j)
          acc[i][j] = __builtin_amdgcn_mfma_f32_16x16x32_bf16(af[i], bfr[j], acc[i][j], 0, 0, 0);
    }
  }

  // epilogue: lane holds D[t = wm + i*16 + q*4 + r][o = o0 + wn + j*16 + m]
  float hb[4], vv[4];
#pragma unroll
  for (int j = 0; j < 4; ++j) {
    int o = o0 + wn + (j << 4) + m;
    hb[j] = hxb[(b << 10) + o];
    vv[j] = v[o];
  }
#pragma unroll
  for (int i = 0; i < 4; ++i) {
#pragma unroll
    for (int r = 0; r < 4; ++r) {
      float s = 0.f;
#pragma unroll
      for (int j = 0; j < 4; ++j) s += fast_tanh(acc[i][j][r] + hb[j]) * vv[j];
      s += __shfl_xor(s, 1);
      s += __shfl_xor(s, 2);
      s += __shfl_xor(s, 4);
      s += __shfl_xor(s, 8);
      if (m == 0) atomicAdd(&part[wm + (i << 4) + (q << 2) + r], s);
    }
  }
  __syncthreads();
  if (tid < 128) atomicAdd(&logits[b * T_ + t0 + tid], part[tid]);
}

// Fused softmax + weighted sum. Grid (H/512, T/256, B). Every block recomputes the
// row softmax from logits (8 KB read); block (0,0,b) also writes the score output.
template <bool PRECONV>
__global__ void wsum_kernel(const float* __restrict__ ctxf, const unsigned short* __restrict__ ctxb,
                            const float* __restrict__ logits,
                            float* __restrict__ score, float* __restrict__ outc) {
  int tid = threadIdx.x;
  int b = blockIdx.z;
  int tch = blockIdx.y << 8;
  __shared__ float wred[4];
  __shared__ float sc[256];

  const float* lb = logits + b * T_;
  float l[8];
  float mx = -3.4e38f;
#pragma unroll
  for (int i = 0; i < 8; ++i) { l[i] = lb[tid + (i << 8)]; mx = fmaxf(mx, l[i]); }
#pragma unroll
  for (int d = 1; d < 64; d <<= 1) mx = fmaxf(mx, __shfl_xor(mx, d));
  if ((tid & 63) == 0) wred[tid >> 6] = mx;
  __syncthreads();
  mx = fmaxf(fmaxf(wred[0], wred[1]), fmaxf(wred[2], wred[3]));
  __syncthreads();
  float e[8];
  float se = 0.f;
#pragma unroll
  for (int i = 0; i < 8; ++i) { e[i] = __expf(l[i] - mx); se += e[i]; }
#pragma unroll
  for (int d = 1; d < 64; d <<= 1) se += __shfl_xor(se, d);
  if ((tid & 63) == 0) wred[tid >> 6] = se;
  __syncthreads();
  se = wred[0] + wred[1] + wred[2] + wred[3];
  float inv = 1.0f / se;
  // thread tid holds e[i] for t = tid + i*256; chunk y needs i == blockIdx.y
  sc[tid] = e[blockIdx.y] * inv;
  if (blockIdx.x == 0 && blockIdx.y == 0) {
#pragma unroll
    for (int i = 0; i < 8; ++i) score[b * T_ + tid + (i << 8)] = e[i] * inv;
  }
  __syncthreads();

  int h = (blockIdx.x << 9) + (tid << 1);
  float s0 = 0.f, s1 = 0.f;
  if (PRECONV) {
    const unsigned short* cp = ctxb + ((size_t)b * T_ + tch) * H_ + h;
#pragma unroll 4
    for (int t = 0; t < 256; ++t) {
      unsigned int u = *(const unsigned int*)(cp + (size_t)t * H_);
      s0 += bf2f((unsigned short)(u & 0xffffu)) * sc[t];
      s1 += bf2f((unsigned short)(u >> 16)) * sc[t];
    }
  } else {
    const float* cp = ctxf + ((size_t)b * T_ + tch) * H_ + h;
#pragma unroll 4
    for (int t = 0; t < 256; ++t) {
      float2 f = *(const float2*)(cp + (size_t)t * H_);
      s0 += f.x * sc[t];
      s1 += f.y * sc[t];
    }
  }
  atomicAdd(&outc[(b << 10) + h], s0);
  atomicAdd(&outc[(b << 10) + h + 1], s1);
}

extern "C" void kernel_launch(void* const* d_in, const int* in_sizes, int n_in,
                              void* d_out, int out_size, void* d_ws, size_t ws_size,
                              hipStream_t stream) {
  const float* x   = (const float*)d_in[0];
  const float* ctx = (const float*)d_in[1];
  // d_in[2] = mask, unused by the reference
  const float* Wq  = (const float*)d_in[3];
  const float* bq  = (const float*)d_in[4];
  const float* Wm  = (const float*)d_in[5];
  const float* bm  = (const float*)d_in[6];
  const float* v   = (const float*)d_in[7];

  float* out_c = (float*)d_out;   // [B,H]
  float* out_s = out_c + B_ * H_; // [B,T]

  char* ws = (char*)d_ws;
  float* hxb = (float*)ws;                                   // 128 KiB
  unsigned short* wmb = (unsigned short*)(ws + 131072);      // 2 MiB
  float* logits = (float*)(ws + 131072 + 2097152);           // 256 KiB
  size_t off_ctxb = 131072 + 2097152 + 262144;
  unsigned short* ctxb = (unsigned short*)(ws + off_ctxb);   // 128 MiB
  size_t need = off_ctxb + (size_t)B_ * T_ * H_ * 2;
  bool preconv = (ws_size >= need);

  int prep_blocks = preconv ? (1248 + 32768) : 1248;
  prep_kernel<<<dim3(prep_blocks), 256, 0, stream>>>(x, Wq, bq, bm, Wm, ctx, hxb, wmb,
                                                     preconv ? ctxb : nullptr, logits, out_c);
  if (preconv) {
    score_kernel<true><<<dim3(4096), 256, 0, stream>>>(ctx, ctxb, wmb, hxb, v, logits);
    wsum_kernel<true><<<dim3(H_ / 512, T_ / 256, B_), 256, 0, stream>>>(ctx, ctxb, logits, out_s, out_c);
  } else {
    score_kernel<false><<<dim3(4096), 256, 0, stream>>>(ctx, ctxb, wmb, hxb, v, logits);
    wsum_kernel<false><<<dim3(H_ / 512, T_ / 256, B_), 256, 0, stream>>>(ctx, ctxb, logits, out_s, out_c);
  }
}

// Round 4
// 651.916 us; speedup vs baseline: 1.1765x; 1.1765x over previous
//
#include <hip/hip_runtime.h>
#include <math.h>

#define B_ 32
#define T_ 2048
#define H_ 1024

typedef __bf16 bf16x8 __attribute__((ext_vector_type(8)));
typedef float f32x4 __attribute__((ext_vector_type(4)));

__device__ __forceinline__ unsigned short f2bf(float f) {
  unsigned int u = __float_as_uint(f);
  u += 0x7fffu + ((u >> 16) & 1u);   // round-to-nearest-even (finite inputs)
  return (unsigned short)(u >> 16);
}

__device__ __forceinline__ float bf2f(unsigned short s) {
  return __uint_as_float(((unsigned int)s) << 16);
}

__device__ __forceinline__ float fast_tanh(float x) {
  float e = __expf(2.0f * x);
  return 1.0f - __fdividef(2.0f, e + 1.0f);  // saturates correctly at +-1
}

// Async 16B global -> LDS. LDS dest is wave-uniform base + lane*16 (HW rule);
// generic->AS casts via integers (LDS generic addr low 32 bits = LDS offset).
__device__ __forceinline__ void async16(const void* g, void* l) {
  typedef const __attribute__((address_space(1))) void* gvp;
  typedef __attribute__((address_space(3))) void* lvp;
  __builtin_amdgcn_global_load_lds((gvp)(unsigned long long)g,
                                   (lvp)(unsigned int)(unsigned long long)l,
                                   16, 0, 0);
}

// blk ranges:
//  [0,8192):      hxb — wave per (b,o): hxb[b,o] = x[b,:].Wq[o,:] + bq[o] + bm[o]
//  [8192,9216):   Wm fp32 -> bf16
//  [9216,9312):   zero logits (64) + out_c (32)
//  [9312,42080):  ctx fp32 -> bf16 (only when ws has room)
__global__ void prep_kernel(const float* __restrict__ x, const float* __restrict__ Wq,
                            const float* __restrict__ bq, const float* __restrict__ bm,
                            const float* __restrict__ Wm, const float* __restrict__ ctx,
                            float* __restrict__ hxb, unsigned short* __restrict__ wmb,
                            unsigned short* __restrict__ ctxb,
                            float* __restrict__ logits, float* __restrict__ outc) {
  int blk = blockIdx.x, tid = threadIdx.x;
  if (blk < 8192) {
    int wave = tid >> 6, lane = tid & 63;
    int pair = (blk << 2) + wave;        // (b,o) pair
    int b = pair >> 10, o = pair & (H_ - 1);
    const float4* wr = (const float4*)(Wq + (size_t)o * H_);
    const float4* xr = (const float4*)(x + (size_t)b * H_);
    float s = 0.f;
#pragma unroll
    for (int s4 = 0; s4 < 4; ++s4) {
      float4 wv = wr[(s4 << 6) + lane];
      float4 xv = xr[(s4 << 6) + lane];
      s += wv.x * xv.x + wv.y * xv.y + wv.z * xv.z + wv.w * xv.w;
    }
#pragma unroll
    for (int d = 1; d < 64; d <<= 1) s += __shfl_xor(s, d);
    if (lane == 0) hxb[(b << 10) + o] = s + bq[o] + bm[o];
  } else if (blk < 9216) {
    int i = ((blk - 8192) << 10) + (tid << 2);
    float4 wv = *(const float4*)(Wm + i);
    *(ushort4*)(wmb + i) = make_ushort4(f2bf(wv.x), f2bf(wv.y), f2bf(wv.z), f2bf(wv.w));
  } else if (blk < 9312) {
    int zblk = blk - 9216;
    if (zblk < 64) {
      *(float4*)(logits + (zblk << 10) + (tid << 2)) = (float4){0.f, 0.f, 0.f, 0.f};
    } else {
      *(float4*)(outc + ((zblk - 64) << 10) + (tid << 2)) = (float4){0.f, 0.f, 0.f, 0.f};
    }
  } else {
    size_t i = ((size_t)(blk - 9312) << 11) + ((size_t)tid << 3);
    float4 a = *(const float4*)(ctx + i);
    float4 c = *(const float4*)(ctx + i + 4);
    *(ushort4*)(ctxb + i) = make_ushort4(f2bf(a.x), f2bf(a.y), f2bf(a.z), f2bf(a.w));
    *(ushort4*)(ctxb + i + 4) = make_ushort4(f2bf(c.x), f2bf(c.y), f2bf(c.z), f2bf(c.w));
  }
}

// Grid 4096: blockIdx.x = ot*512 + b*16 + tt. One 128t x 128o tile per block.
// A (ctx bf16) and B (Wm bf16) staged via global_load_lds with XOR swizzle:
// physical 16B-granule g_phys = g_log ^ (row & 7) -> b128 frag reads hit the
// 8-access/bank LDS floor (conflict-free). Partial logits atomicAdd'ed to global.
template <bool PRECONV>
__global__ __launch_bounds__(256) void score_kernel(
    const float* __restrict__ ctxf, const unsigned short* __restrict__ ctxb,
    const unsigned short* __restrict__ wmb,
    const float* __restrict__ hxb, const float* __restrict__ v,
    float* logits) {
  __shared__ __align__(16) unsigned short As[128 * 64];
  __shared__ __align__(16) unsigned short Bs[128 * 64];
  __shared__ float part[128];

  int tid = threadIdx.x;
  int xx = blockIdx.x;
  int ot = xx >> 9;
  int bt = xx & 511;
  int b = bt >> 4;
  int t0 = (bt & 15) << 7;
  int o0 = ot << 7;
  if (tid < 128) part[tid] = 0.f;

  int lane = tid & 63;
  int wave = tid >> 6;
  int wm = (wave >> 1) << 6;  // wave t-offset (0/64)
  int wn = (wave & 1) << 6;   // wave o-offset (0/64)
  int q = lane >> 4;
  int m = lane & 15;

  const unsigned short* cb = PRECONV ? (ctxb + ((size_t)b * T_ + t0) * H_) : nullptr;
  const float* cf = PRECONV ? nullptr : (ctxf + ((size_t)b * T_ + t0) * H_);
  const unsigned short* wb = wmb + (size_t)o0 * H_;

  f32x4 acc[4][4];
#pragma unroll
  for (int i = 0; i < 4; ++i)
#pragma unroll
    for (int j = 0; j < 4; ++j) acc[i][j] = (f32x4){0.f, 0.f, 0.f, 0.f};

  for (int k0 = 0; k0 < H_; k0 += 64) {
    __syncthreads();
#pragma unroll
    for (int i = 0; i < 4; ++i) {
      int ig = (wave << 2) + i;          // issue-group 0..15 (64 granules each)
      int p = (ig << 6) + lane;          // physical granule 0..1023
      int row = p >> 3;
      int gl = (p & 7) ^ (row & 7);      // logical granule (swizzle inverse)
      size_t goff = (size_t)row * H_ + k0 + (gl << 3);
      if (PRECONV) {
        async16(cb + goff, (char*)As + ((size_t)ig << 10));
      } else {
        // manual convert staging into the same swizzled layout
        int arow = (tid >> 3) + (i << 5);
        int agl = tid & 7;
        int agp = agl ^ (arow & 7);
        const float* src = cf + (size_t)arow * H_ + k0 + (agl << 3);
        float4 f0 = *(const float4*)(src);
        float4 f1 = *(const float4*)(src + 4);
        unsigned short* dst = As + (arow << 6) + (agp << 3);
        *(ushort4*)(dst) = make_ushort4(f2bf(f0.x), f2bf(f0.y), f2bf(f0.z), f2bf(f0.w));
        *(ushort4*)(dst + 4) = make_ushort4(f2bf(f1.x), f2bf(f1.y), f2bf(f1.z), f2bf(f1.w));
      }
      async16(wb + goff, (char*)Bs + ((size_t)ig << 10));
    }
    __syncthreads();
#pragma unroll
    for (int kk = 0; kk < 2; ++kk) {
      bf16x8 af[4], bfr[4];
#pragma unroll
      for (int i = 0; i < 4; ++i) {
        int row = wm + (i << 4) + m;
        int gp = ((kk << 2) + q) ^ (row & 7);
        af[i] = *(const bf16x8*)(As + (row << 6) + (gp << 3));
      }
#pragma unroll
      for (int j = 0; j < 4; ++j) {
        int row = wn + (j << 4) + m;
        int gp = ((kk << 2) + q) ^ (row & 7);
        bfr[j] = *(const bf16x8*)(Bs + (row << 6) + (gp << 3));
      }
#pragma unroll
      for (int i = 0; i < 4; ++i)
#pragma unroll
        for (int j = 0; j < 4; ++j)
          acc[i][j] = __builtin_amdgcn_mfma_f32_16x16x32_bf16(af[i], bfr[j], acc[i][j], 0, 0, 0);
    }
  }

  // epilogue: lane holds D[t = wm + i*16 + q*4 + r][o = o0 + wn + j*16 + m]
  float hb[4], vv[4];
#pragma unroll
  for (int j = 0; j < 4; ++j) {
    int o = o0 + wn + (j << 4) + m;
    hb[j] = hxb[(b << 10) + o];
    vv[j] = v[o];
  }
#pragma unroll
  for (int i = 0; i < 4; ++i) {
#pragma unroll
    for (int r = 0; r < 4; ++r) {
      float s = 0.f;
#pragma unroll
      for (int j = 0; j < 4; ++j) s += fast_tanh(acc[i][j][r] + hb[j]) * vv[j];
      s += __shfl_xor(s, 1);
      s += __shfl_xor(s, 2);
      s += __shfl_xor(s, 4);
      s += __shfl_xor(s, 8);
      if (m == 0) atomicAdd(&part[wm + (i << 4) + (q << 2) + r], s);
    }
  }
  __syncthreads();
  if (tid < 128) atomicAdd(&logits[b * T_ + t0 + tid], part[tid]);
}

// Fused softmax + weighted sum. Grid (T/128, B). Each block recomputes the row
// softmax from logits (8 KB), handles a 128-t chunk; thread owns 4 h columns.
template <bool PRECONV>
__global__ void wsum_kernel(const float* __restrict__ ctxf, const unsigned short* __restrict__ ctxb,
                            const float* __restrict__ logits,
                            float* __restrict__ score, float* __restrict__ outc) {
  int tid = threadIdx.x;
  int b = blockIdx.y;
  int tc = blockIdx.x << 7;
  __shared__ float wred[4];
  __shared__ float sc[128];

  const float* lb = logits + b * T_;
  float l[8];
  float mx = -3.4e38f;
#pragma unroll
  for (int i = 0; i < 8; ++i) { l[i] = lb[tid + (i << 8)]; mx = fmaxf(mx, l[i]); }
#pragma unroll
  for (int d = 1; d < 64; d <<= 1) mx = fmaxf(mx, __shfl_xor(mx, d));
  if ((tid & 63) == 0) wred[tid >> 6] = mx;
  __syncthreads();
  mx = fmaxf(fmaxf(wred[0], wred[1]), fmaxf(wred[2], wred[3]));
  __syncthreads();
  float e[8];
  float se = 0.f;
#pragma unroll
  for (int i = 0; i < 8; ++i) { e[i] = __expf(l[i] - mx); se += e[i]; }
#pragma unroll
  for (int d = 1; d < 64; d <<= 1) se += __shfl_xor(se, d);
  if ((tid & 63) == 0) wred[tid >> 6] = se;
  __syncthreads();
  se = wred[0] + wred[1] + wred[2] + wred[3];
  float inv = 1.0f / se;
#pragma unroll
  for (int i = 0; i < 8; ++i) {
    int tg = tid + (i << 8);
    if ((tg >> 7) == (int)blockIdx.x) sc[tg & 127] = e[i] * inv;
  }
  if (blockIdx.x == 0) {
#pragma unroll
    for (int i = 0; i < 8; ++i) score[b * T_ + tid + (i << 8)] = e[i] * inv;
  }
  __syncthreads();

  int h = tid << 2;
  float s0 = 0.f, s1 = 0.f, s2 = 0.f, s3 = 0.f;
  if (PRECONV) {
    const unsigned short* cp = ctxb + ((size_t)b * T_ + tc) * H_ + h;
#pragma unroll 4
    for (int t = 0; t < 128; ++t) {
      uint2 u = *(const uint2*)(cp + (size_t)t * H_);
      float w = sc[t];
      s0 += bf2f((unsigned short)(u.x & 0xffffu)) * w;
      s1 += bf2f((unsigned short)(u.x >> 16)) * w;
      s2 += bf2f((unsigned short)(u.y & 0xffffu)) * w;
      s3 += bf2f((unsigned short)(u.y >> 16)) * w;
    }
  } else {
    const float* cp = ctxf + ((size_t)b * T_ + tc) * H_ + h;
#pragma unroll 4
    for (int t = 0; t < 128; ++t) {
      float4 f = *(const float4*)(cp + (size_t)t * H_);
      float w = sc[t];
      s0 += f.x * w; s1 += f.y * w; s2 += f.z * w; s3 += f.w * w;
    }
  }
  float* op = outc + (b << 10) + h;
  atomicAdd(op + 0, s0);
  atomicAdd(op + 1, s1);
  atomicAdd(op + 2, s2);
  atomicAdd(op + 3, s3);
}

extern "C" void kernel_launch(void* const* d_in, const int* in_sizes, int n_in,
                              void* d_out, int out_size, void* d_ws, size_t ws_size,
                              hipStream_t stream) {
  const float* x   = (const float*)d_in[0];
  const float* ctx = (const float*)d_in[1];
  // d_in[2] = mask, unused by the reference
  const float* Wq  = (const float*)d_in[3];
  const float* bq  = (const float*)d_in[4];
  const float* Wm  = (const float*)d_in[5];
  const float* bm  = (const float*)d_in[6];
  const float* v   = (const float*)d_in[7];

  float* out_c = (float*)d_out;   // [B,H]
  float* out_s = out_c + B_ * H_; // [B,T]

  char* ws = (char*)d_ws;
  float* hxb = (float*)ws;                                   // 128 KiB
  unsigned short* wmb = (unsigned short*)(ws + 131072);      // 2 MiB
  float* logits = (float*)(ws + 131072 + 2097152);           // 256 KiB
  size_t off_ctxb = 131072 + 2097152 + 262144;
  unsigned short* ctxb = (unsigned short*)(ws + off_ctxb);   // 128 MiB
  size_t need = off_ctxb + (size_t)B_ * T_ * H_ * 2;
  bool preconv = (ws_size >= need);

  int prep_blocks = preconv ? (9312 + 32768) : 9312;
  prep_kernel<<<dim3(prep_blocks), 256, 0, stream>>>(x, Wq, bq, bm, Wm, ctx, hxb, wmb,
                                                     preconv ? ctxb : nullptr, logits, out_c);
  if (preconv) {
    score_kernel<true><<<dim3(4096), 256, 0, stream>>>(ctx, ctxb, wmb, hxb, v, logits);
    wsum_kernel<true><<<dim3(T_ / 128, B_), 256, 0, stream>>>(ctx, ctxb, logits, out_s, out_c);
  } else {
    score_kernel<false><<<dim3(4096), 256, 0, stream>>>(ctx, ctxb, wmb, hxb, v, logits);
    wsum_kernel<false><<<dim3(T_ / 128, B_), 256, 0, stream>>>(ctx, ctxb, logits, out_s, out_c);
  }
}